// Round 25
// baseline (126.219 us; speedup 1.0000x reference)
//
#include <hip/hip_runtime.h>

#define NF 64      // hidden width (both layers)
#define NBLK 256   // chunks for the two-pass bucket sort
#define SH 8       // bucket = dst >> SH  (256 nodes per bucket)
#define BMSK 255
#define MAXNB 2048 // LDS histogram capacity (NB = ceil(n/256) <= 2048 -> n <= 524288)

typedef unsigned short ushort_t;
typedef __attribute__((ext_vector_type(8))) short short8;   // 8 bf16 = 4 VGPR (MFMA A/B frag)
typedef __attribute__((ext_vector_type(4))) float f32x4;    // MFMA C/D frag

__device__ inline ushort_t f2bf(float f) {               // RNE f32 -> bf16
    unsigned u = __float_as_uint(f);
    return (ushort_t)((u + 0x7fffu + ((u >> 16) & 1u)) >> 16);
}
__device__ inline float bfhi(unsigned x) { return __uint_as_float(x & 0xffff0000u); }
__device__ inline float bflo(unsigned x) { return __uint_as_float(x << 16); }

#define PACK8(b, ua, ub) \
    b[0] = (short)f2bf(ua.x); b[1] = (short)f2bf(ua.y); \
    b[2] = (short)f2bf(ua.z); b[3] = (short)f2bf(ua.w); \
    b[4] = (short)f2bf(ub.x); b[5] = (short)f2bf(ub.y); \
    b[6] = (short)f2bf(ub.z); b[7] = (short)f2bf(ub.w);

// =================== scan utilities ===================

__device__ inline int wave_incl_scan(int x, int lane) {
#pragma unroll
    for (int o = 1; o < 64; o <<= 1) { int y = __shfl_up(x, o, 64); if (lane >= o) x += y; }
    return x;
}

// 1024 elements per block (256 threads x 4); in-place safe
__global__ __launch_bounds__(256) void k_scan_a(const int* __restrict__ in, int* __restrict__ out,
                                                int* __restrict__ bsums, int n) {
    int t = threadIdx.x, lane = t & 63, wv = t >> 6;
    int base = blockIdx.x * 1024 + t * 4;
    int v[4]; int s = 0;
#pragma unroll
    for (int k = 0; k < 4; ++k) { int i = base + k; int x = (i < n) ? in[i] : 0; v[k] = s; s += x; }
    int incl = wave_incl_scan(s, lane);
    __shared__ int ws[4];
    if (lane == 63) ws[wv] = incl;
    __syncthreads();
    int wofs = 0;
#pragma unroll
    for (int w = 0; w < 4; ++w) if (w < wv) wofs += ws[w];
    int texcl = wofs + incl - s;
#pragma unroll
    for (int k = 0; k < 4; ++k) { int i = base + k; if (i < n) out[i] = texcl + v[k]; }
    if (t == 255) bsums[blockIdx.x] = wofs + incl;
}

// add block sums (prefix computed locally from raw bsums: <=2048 entries, one wave);
// also emit bucket pointers (bptr[b] = scanned hmat[b*NBLK], bptr[NB] = E)
__global__ __launch_bounds__(256) void k_scan_addb(int* __restrict__ data, const int* __restrict__ bsums,
                                                   int* __restrict__ bptr, int ntot, int E) {
    __shared__ int off_s;
    int t = threadIdx.x;
    int myChunk = (int)(blockIdx.x >> 2);          // this block's 1024-chunk index
    if (t < 64) {
        int s = 0;
        for (int i = t; i < myChunk; i += 64) s += bsums[i];
#pragma unroll
        for (int o = 32; o > 0; o >>= 1) s += __shfl_xor(s, o, 64);
        if (t == 0) off_s = s;
    }
    __syncthreads();
    int off = off_s;
    int i = blockIdx.x * 256 + t;
    if (i < ntot) {
        int v = data[i] + off;
        data[i] = v;
        if ((i & (NBLK - 1)) == 0) bptr[i / NBLK] = v;
    }
    if (i == 0) bptr[ntot / NBLK] = E;
}

// =================== contention-free bucket sort (bucket = dst >> SH, 256 nodes/bucket) ===================
// prologue: pre-swizzle W1/W2 into bf16 MFMA-fragment order in global ws (once, not per GEMM block)

__global__ __launch_bounds__(256) void k_histA(const int* __restrict__ dst, int* __restrict__ hmat,
                                               int E, int NB, int chunk,
                                               const float* __restrict__ W1, const float* __restrict__ W2,
                                               ushort_t* __restrict__ w1f, ushort_t* __restrict__ w2f) {
    __shared__ int h[MAXNB];
    int blk = blockIdx.x;
    // ---- W pre-swizzle (12288 elems over 65536 threads) ----
    int gid = blk * 256 + threadIdx.x;
    if (gid < 8192) {                                     // W1: [128][64]
        int k = gid >> 6, c = gid & 63;
        int f = ((k >> 5) << 2) | (c >> 4);
        int ln = (c & 15) | (((k >> 3) & 3) << 4);
        w1f[f * 512 + ln * 8 + (k & 7)] = f2bf(W1[gid]);
    } else if (gid < 12288) {                             // W2: [64][64]
        int i2 = gid - 8192;
        int k = i2 >> 6, c = i2 & 63;
        int f = ((k >> 5) << 2) | (c >> 4);
        int ln = (c & 15) | (((k >> 3) & 3) << 4);
        w2f[f * 512 + ln * 8 + (k & 7)] = f2bf(W2[i2]);
    }

    for (int i = threadIdx.x; i < NB; i += 256) h[i] = 0;
    __syncthreads();
    int beg = blk * chunk, end = beg + chunk; if (end > E) end = E;
    for (int e = beg + threadIdx.x; e < end; e += 256) atomicAdd(&h[dst[e] >> SH], 1);
    __syncthreads();
    for (int i = threadIdx.x; i < NB; i += 256) hmat[i * NBLK + blk] = h[i];
}

__global__ __launch_bounds__(256) void k_placeB(const int* __restrict__ src, const int* __restrict__ dst,
                                                const int* __restrict__ hmat, int* __restrict__ pairs,
                                                int E, int NB, int chunk) {
    __shared__ int cur[MAXNB];
    int blk = blockIdx.x;
    for (int i = threadIdx.x; i < NB; i += 256) cur[i] = hmat[i * NBLK + blk];
    __syncthreads();
    int beg = blk * chunk, end = beg + chunk; if (end > E) end = E;
    for (int e = beg + threadIdx.x; e < end; e += 256) {
        int s = src[e], d = dst[e];
        int off = atomicAdd(&cur[d >> SH], 1);
        pairs[off] = (s << SH) | (d & BMSK);
    }
}

// =================== fused CSR + GEMM1 (load-hoisted) ===================
// One block per 256-node bucket:
//   phase 1: node hist + 256-scan -> row_ptr/cnt/dinv (dinv cached in LDS ds[])
//   phase 1.5: ISSUE all 32 X float4 loads (4 tiles x 8 chunks) + 16 A-frag loads
//   phase 2: col placement via LDS cursors  (X/frag loads in flight -> latency hidden)
//   phase 3: pack + MFMA + store per tile
__global__ __launch_bounds__(256) void k_csrmm(
    const int* __restrict__ bptr, const int* __restrict__ pairs,
    int* __restrict__ row_ptr, int* __restrict__ cnt,
    float* __restrict__ dinv, int* __restrict__ col,
    const float* __restrict__ X, const ushort_t* __restrict__ w1f,
    ushort_t* __restrict__ hsb, int n)
{
    __shared__ int h[256];
    __shared__ int cur[256];
    __shared__ float ds[256];
    __shared__ int ws[4];
    int b = blockIdx.x, t = threadIdx.x;
    h[t] = 0;
    __syncthreads();
    int beg = bptr[b], end = bptr[b + 1];
    for (int j = beg + t; j < end; j += 256) atomicAdd(&h[pairs[j] & BMSK], 1);
    __syncthreads();
    int c = h[t];
    int incl = wave_incl_scan(c, t & 63);
    if ((t & 63) == 63) ws[t >> 6] = incl;
    __syncthreads();
    int wofs = 0;
#pragma unroll
    for (int w = 0; w < 4; ++w) if (w < (t >> 6)) wofs += ws[w];
    int ex = wofs + incl - c;
    int node0 = b << SH;
    int node = node0 + t;
    float di_t = rsqrtf(1.0f + (float)c);
    if (node < n) {
        row_ptr[node] = beg + ex;
        cnt[node] = c;
        dinv[node] = di_t;
    }
    cur[t] = beg + ex;
    ds[t] = di_t;
    __syncthreads();

    // ---- phase 1.5: issue all X loads (4 tiles x 8 chunks = 512 B/lane in flight) ----
    int lane = t & 63, wv = t >> 6;
    int r16 = lane & 15, kg = lane >> 4;
    const float* pX[4];
#pragma unroll
    for (int q = 0; q < 4; ++q) {
        int lrow = (wv + q * 4) * 16 + r16;
        int row = node0 + lrow;
        int r = (row < n) ? row : (n - 1);           // clamp: dup loads, stores guarded
        pX[q] = X + (size_t)r * 128 + kg * 8;
    }
    float4 u[4][8];
#pragma unroll
    for (int q = 0; q < 4; ++q) {
#pragma unroll
        for (int j = 0; j < 4; ++j) {
            u[q][2 * j]     = *(const float4*)(pX[q] + j * 32);
            u[q][2 * j + 1] = *(const float4*)(pX[q] + j * 32 + 4);
        }
    }
    short8 a0[4], a1[4], a2[4], a3[4];
#pragma unroll
    for (int f = 0; f < 4; ++f) {
        a0[f] = *(const short8*)(w1f + (0 + f) * 512 + lane * 8);
        a1[f] = *(const short8*)(w1f + (4 + f) * 512 + lane * 8);
        a2[f] = *(const short8*)(w1f + (8 + f) * 512 + lane * 8);
        a3[f] = *(const short8*)(w1f + (12 + f) * 512 + lane * 8);
    }

    // ---- phase 2: place col (loads above in flight) ----
    for (int j = beg + t; j < end; j += 256) {
        int pk = pairs[j];
        int p = atomicAdd(&cur[pk & BMSK], 1);
        col[p] = pk >> SH;
    }

    // ---- phase 3: pack + MFMA + store per tile ----
#pragma unroll
    for (int q = 0; q < 4; ++q) {
        short8 b0, b1, b2, b3;
        PACK8(b0, u[q][0], u[q][1]); PACK8(b1, u[q][2], u[q][3]);
        PACK8(b2, u[q][4], u[q][5]); PACK8(b3, u[q][6], u[q][7]);

        f32x4 z = {0.f, 0.f, 0.f, 0.f};
        f32x4 acc[4];
#pragma unroll
        for (int f = 0; f < 4; ++f)
            acc[f] = __builtin_amdgcn_mfma_f32_16x16x32_bf16(a0[f], b0, z, 0, 0, 0);
#pragma unroll
        for (int f = 0; f < 4; ++f)
            acc[f] = __builtin_amdgcn_mfma_f32_16x16x32_bf16(a1[f], b1, acc[f], 0, 0, 0);
#pragma unroll
        for (int f = 0; f < 4; ++f)
            acc[f] = __builtin_amdgcn_mfma_f32_16x16x32_bf16(a2[f], b2, acc[f], 0, 0, 0);
#pragma unroll
        for (int f = 0; f < 4; ++f)
            acc[f] = __builtin_amdgcn_mfma_f32_16x16x32_bf16(a3[f], b3, acc[f], 0, 0, 0);

        int lrow = (wv + q * 4) * 16 + r16;
        int row = node0 + lrow;
        if (row < n) {
            float di = ds[lrow];
#pragma unroll
            for (int f = 0; f < 4; ++f) {
                ushort4 o;
                o.x = f2bf(acc[f][0] * di); o.y = f2bf(acc[f][1] * di);
                o.z = f2bf(acc[f][2] * di); o.w = f2bf(acc[f][3] * di);
                *(ushort4*)(hsb + (size_t)row * NF + f * 16 + kg * 4) = o;
            }
        }
    }
}

// =================== fused pull1 + GEMM2 ===================
// Block = 256 threads = 16 dst nodes = one 16-row MFMA tile.
// Phase A (pull): act_row(d) = relu(dinv[d]*(hs[d]+sum hs[src])+b1), written in B-frag order
//   to LDS bfrag (2 KB). Phase B: A-frags from pre-swizzled global w2f (prefetched before
//   the gather loop); wave wv computes column slab [wv*16, wv*16+16).
__global__ __launch_bounds__(256) void k_pullmm(
    const ushort_t* __restrict__ hs, const float* __restrict__ dinv,
    const int* __restrict__ row_ptr, const int* __restrict__ cnt,
    const int* __restrict__ col, const float* __restrict__ bias,
    const ushort_t* __restrict__ w2f, ushort_t* __restrict__ out, int n)
{
    __shared__ ushort_t bfrag[1024];             // act tile in B-frag order (2 KB)
    int t = threadIdx.x;
    int lane = t & 63, wv = t >> 6;

    // prefetch A-frags (L2-resident; latency hides under the gather loop)
    short8 aflo = *(const short8*)(w2f + wv * 512 + lane * 8);
    short8 afhi = *(const short8*)(w2f + (4 + wv) * 512 + lane * 8);

    // ---- phase A: pull (one 16-lane group per node) ----
    int d = blockIdx.x * 16 + (t >> 4);
    int lt = t & 15;
    int fo = lt << 2;
    int grpbase = t & 48;
    const char* __restrict__ hp = (const char*)hs;
    unsigned lt8 = (unsigned)lt << 3;
    float rx = 0.f, ry = 0.f, rz = 0.f, rw = 0.f;
    if (d < n) {
        uint2 sv = *(const uint2*)(hp + (((unsigned)d << 7) + lt8));
        float4 acc = make_float4(bflo(sv.x), bfhi(sv.x), bflo(sv.y), bfhi(sv.y));
        int beg = row_ptr[d], deg = cnt[d];
        for (int jb = 0; jb < deg; jb += 16) {
            int m = deg - jb; if (m > 16) m = 16;
            int idx = (lt < m) ? col[beg + jb + lt] : 0;
            uint2 v[16];
#pragma unroll
            for (int u = 0; u < 16; ++u) {
                int kk = (u < m) ? u : (m - 1);              // clamp: dup loads hit L1
                int s = __shfl(idx, grpbase + kk, 64);
                v[u] = *(const uint2*)(hp + (((unsigned)s << 7) + lt8));
            }
#pragma unroll
            for (int u = 0; u < 16; ++u) {
                if (u < m) {
                    acc.x += bflo(v[u].x); acc.y += bfhi(v[u].x);
                    acc.z += bflo(v[u].y); acc.w += bfhi(v[u].y);
                }
            }
        }
        float di = dinv[d];
        float4 bv = *(const float4*)(bias + fo);
        rx = fmaxf(fmaf(acc.x, di, bv.x), 0.0f);
        ry = fmaxf(fmaf(acc.y, di, bv.y), 0.0f);
        rz = fmaxf(fmaf(acc.z, di, bv.z), 0.0f);
        rw = fmaxf(fmaf(acc.w, di, bv.w), 0.0f);
    }
    {
        ushort4 o;
        o.x = f2bf(rx); o.y = f2bf(ry); o.z = f2bf(rz); o.w = f2bf(rw);
        int g = t >> 4;
        int ks = lt >> 3, kg2 = (lt >> 1) & 3, half = lt & 1;
        *(ushort4*)(bfrag + ks * 512 + (((kg2 << 4) | g) << 3) + (half << 2)) = o;
    }
    __syncthreads();

    // ---- phase B: MFMA (wave wv -> columns [wv*16, wv*16+16)) ----
    int r16 = lane & 15, kg = lane >> 4;
    short8 bb0 = *(const short8*)(bfrag + lane * 8);         // ks=0, conflict-free
    short8 bb1 = *(const short8*)(bfrag + 512 + lane * 8);   // ks=1

    f32x4 z = {0.f, 0.f, 0.f, 0.f};
    f32x4 acc2 = __builtin_amdgcn_mfma_f32_16x16x32_bf16(aflo, bb0, z, 0, 0, 0);
    acc2 = __builtin_amdgcn_mfma_f32_16x16x32_bf16(afhi, bb1, acc2, 0, 0, 0);

    int row = blockIdx.x * 16 + r16;
    if (row < n) {
        float di = dinv[row];
        ushort4 o;
        o.x = f2bf(acc2[0] * di); o.y = f2bf(acc2[1] * di);
        o.z = f2bf(acc2[2] * di); o.w = f2bf(acc2[3] * di);
        *(ushort4*)((char*)out + (((unsigned)row << 7) + ((unsigned)wv << 5) + ((unsigned)kg << 3))) = o;
    }
}

// =================== pull2 + fused decode: out[d] = relu(dinv*(...)+b2) . Wd + bd ===================
__global__ __launch_bounds__(256) void k_pull2(
    const ushort_t* __restrict__ hs, const float* __restrict__ dinv,
    const int* __restrict__ row_ptr, const int* __restrict__ cnt,
    const int* __restrict__ col, const float* __restrict__ bias,
    const float* __restrict__ Wd, const float* __restrict__ bd,
    float* __restrict__ outv, int n)
{
    int d = blockIdx.x * 16 + (threadIdx.x >> 4);
    if (d >= n) return;
    int lt = threadIdx.x & 15;            // lane in group
    int fo = lt << 2;                     // feature offset (4 features/lane)
    int grpbase = threadIdx.x & 48;       // group base lane within wave
    const char* __restrict__ hp = (const char*)hs;
    unsigned lt8 = (unsigned)lt << 3;
    int beg = row_ptr[d], deg = cnt[d];

    // self-loop (bf16 row, 8B/lane)
    uint2 sv = *(const uint2*)(hp + (((unsigned)d << 7) + lt8));
    float4 acc = make_float4(bflo(sv.x), bfhi(sv.x), bflo(sv.y), bfhi(sv.y));

    for (int jb = 0; jb < deg; jb += 16) {
        int m = deg - jb; if (m > 16) m = 16;
        int idx = (lt < m) ? col[beg + jb + lt] : 0;
        uint2 v[16];
#pragma unroll
        for (int u = 0; u < 16; ++u) {
            int kk = (u < m) ? u : (m - 1);                  // clamp: dup loads hit L1
            int s = __shfl(idx, grpbase + kk, 64);
            v[u] = *(const uint2*)(hp + (((unsigned)s << 7) + lt8));
        }
#pragma unroll
        for (int u = 0; u < 16; ++u) {
            if (u < m) {
                acc.x += bflo(v[u].x); acc.y += bfhi(v[u].x);
                acc.z += bflo(v[u].y); acc.w += bfhi(v[u].y);
            }
        }
    }

    float di = dinv[d];
    float4 bv = *(const float4*)(bias + fo);
    float rx = fmaxf(fmaf(acc.x, di, bv.x), 0.0f);
    float ry = fmaxf(fmaf(acc.y, di, bv.y), 0.0f);
    float rz = fmaxf(fmaf(acc.z, di, bv.z), 0.0f);
    float rw = fmaxf(fmaf(acc.w, di, bv.w), 0.0f);

    float4 wv = *(const float4*)(Wd + fo);
    float vsum = rx * wv.x + ry * wv.y + rz * wv.z + rw * wv.w;
#pragma unroll
    for (int o = 1; o < 16; o <<= 1) vsum += __shfl_xor(vsum, o, 64);
    if (lt == 0) outv[d] = vsum + bd[0];
}

extern "C" void kernel_launch(void* const* d_in, const int* in_sizes, int n_in,
                              void* d_out, int out_size, void* d_ws, size_t ws_size,
                              hipStream_t stream) {
    const float* x  = (const float*)d_in[0];
    const int*   ei = (const int*)d_in[1];
    const float* W1 = (const float*)d_in[2];
    const float* b1 = (const float*)d_in[3];
    const float* W2 = (const float*)d_in[4];
    const float* b2 = (const float*)d_in[5];
    const float* Wd = (const float*)d_in[6];
    const float* bd = (const float*)d_in[7];
    float* out = (float*)d_out;

    int n = in_sizes[0] / 128;
    int E = in_sizes[1] / 2;
    const int* src = ei;
    const int* dst = ei + E;

    int NB = (n + (1 << SH) - 1) >> SH;     // dst buckets of 256 nodes (~391)
    int chunk = (E + NBLK - 1) / NBLK;
    int ntot = NB * NBLK;                   // hist matrix size (~100k)
    int nsb = (ntot + 1023) / 1024;         // scan blocks over hmat (<= 2048)

    // workspace layout (4-byte elems)
    // bufH: hsb. bufA: hs2b (lower half) + pairs (upper half).
    // pairs is read by k_csrmm while it writes hsb -> must not alias bufH.
    float* dinv    = (float*)d_ws;                    // n
    float* bufH    = dinv + n;                        // 64n f32 region
    float* bufA    = bufH + (size_t)n * NF;           // 64n f32 region
    int*   counts  = (int*)(bufA + (size_t)n * NF);   // n
    int*   row_ptr = counts + n;                      // n
    int*   col     = row_ptr + n;                     // E
    int*   hmat    = col + E;                         // NB*NBLK
    int*   bptr    = hmat + ntot;                     // NB+1
    int*   bsums   = bptr + NB + 1;                   // <=2048
    int*   wfrags  = bsums + 2048;                    // 6144 ints: w1f (4096) + w2f (2048)
    ushort_t* w1f  = (ushort_t*)wfrags;               // 8192 bf16 pre-swizzled W1 frags
    ushort_t* w2f  = w1f + 8192;                      // 4096 bf16 pre-swizzled W2 frags
    ushort_t* hsb  = (ushort_t*)bufH;                 // 64n bf16 layer-1 hs
    ushort_t* hs2b = (ushort_t*)bufA;                 // 64n bf16 layer-2 hs (lower 32n f32)
    int*   pairs   = (int*)(bufA + (size_t)n * 32);   // E ints in upper half of bufA region

    // ---- bucket sort by dst (contention-free) + W frag pre-swizzle ----
    k_histA<<<NBLK, 256, 0, stream>>>(dst, hmat, E, NB, chunk, W1, W2, w1f, w2f);
    k_scan_a<<<nsb, 256, 0, stream>>>(hmat, hmat, bsums, ntot);
    k_scan_addb<<<(ntot + 255) / 256, 256, 0, stream>>>(hmat, bsums, bptr, ntot, E);
    k_placeB<<<NBLK, 256, 0, stream>>>(src, dst, hmat, pairs, E, NB, chunk);

    // ---- fused node CSR + dinv + GEMM1 (MFMA, load-hoisted) ----
    k_csrmm<<<NB, 256, 0, stream>>>(bptr, pairs, row_ptr, counts, dinv, col,
                                    x, w1f, hsb, n);

    // ---- fused pull1 (+b1, relu) + GEMM2 (MFMA): hs2 = bf16((act @ W2) * dinv) ----
    k_pullmm<<<(n + 15) / 16, 256, 0, stream>>>(hsb, dinv, row_ptr, counts, col, b1,
                                                w2f, hs2b, n);

    // ---- pull2 (+b2, relu) + fused decode ----
    k_pull2<<<(n + 15) / 16, 256, 0, stream>>>(hs2b, dinv, row_ptr, counts, col, b2,
                                               Wd, bd, out, n);
}

// Round 26
// 123.283 us; speedup vs baseline: 1.0238x; 1.0238x over previous
//
#include <hip/hip_runtime.h>

#define NF 64      // hidden width (both layers)
#define NBLK 256   // chunks for the two-pass bucket sort
#define SH 8       // bucket = dst >> SH  (256 nodes per bucket)
#define BMSK 255
#define MAXNB 2048 // LDS histogram capacity (NB = ceil(n/256) <= 2048 -> n <= 524288)

typedef unsigned short ushort_t;
typedef __attribute__((ext_vector_type(8))) short short8;   // 8 bf16 = 4 VGPR (MFMA A/B frag)
typedef __attribute__((ext_vector_type(4))) float f32x4;    // MFMA C/D frag

__device__ inline ushort_t f2bf(float f) {               // RNE f32 -> bf16
    unsigned u = __float_as_uint(f);
    return (ushort_t)((u + 0x7fffu + ((u >> 16) & 1u)) >> 16);
}
__device__ inline float bfhi(unsigned x) { return __uint_as_float(x & 0xffff0000u); }
__device__ inline float bflo(unsigned x) { return __uint_as_float(x << 16); }

#define PACK8(b, ua, ub) \
    b[0] = (short)f2bf(ua.x); b[1] = (short)f2bf(ua.y); \
    b[2] = (short)f2bf(ua.z); b[3] = (short)f2bf(ua.w); \
    b[4] = (short)f2bf(ub.x); b[5] = (short)f2bf(ub.y); \
    b[6] = (short)f2bf(ub.z); b[7] = (short)f2bf(ub.w);

// =================== scan utilities ===================

__device__ inline int wave_incl_scan(int x, int lane) {
#pragma unroll
    for (int o = 1; o < 64; o <<= 1) { int y = __shfl_up(x, o, 64); if (lane >= o) x += y; }
    return x;
}

// 1024 elements per block (256 threads x 4); in-place safe
__global__ __launch_bounds__(256) void k_scan_a(const int* __restrict__ in, int* __restrict__ out,
                                                int* __restrict__ bsums, int n) {
    int t = threadIdx.x, lane = t & 63, wv = t >> 6;
    int base = blockIdx.x * 1024 + t * 4;
    int v[4]; int s = 0;
#pragma unroll
    for (int k = 0; k < 4; ++k) { int i = base + k; int x = (i < n) ? in[i] : 0; v[k] = s; s += x; }
    int incl = wave_incl_scan(s, lane);
    __shared__ int ws[4];
    if (lane == 63) ws[wv] = incl;
    __syncthreads();
    int wofs = 0;
#pragma unroll
    for (int w = 0; w < 4; ++w) if (w < wv) wofs += ws[w];
    int texcl = wofs + incl - s;
#pragma unroll
    for (int k = 0; k < 4; ++k) { int i = base + k; if (i < n) out[i] = texcl + v[k]; }
    if (t == 255) bsums[blockIdx.x] = wofs + incl;
}

// add block sums (prefix computed locally from raw bsums: <=2048 entries, one wave);
// also emit bucket pointers (bptr[b] = scanned hmat[b*NBLK], bptr[NB] = E)
__global__ __launch_bounds__(256) void k_scan_addb(int* __restrict__ data, const int* __restrict__ bsums,
                                                   int* __restrict__ bptr, int ntot, int E) {
    __shared__ int off_s;
    int t = threadIdx.x;
    int myChunk = (int)(blockIdx.x >> 2);          // this block's 1024-chunk index
    if (t < 64) {
        int s = 0;
        for (int i = t; i < myChunk; i += 64) s += bsums[i];
#pragma unroll
        for (int o = 32; o > 0; o >>= 1) s += __shfl_xor(s, o, 64);
        if (t == 0) off_s = s;
    }
    __syncthreads();
    int off = off_s;
    int i = blockIdx.x * 256 + t;
    if (i < ntot) {
        int v = data[i] + off;
        data[i] = v;
        if ((i & (NBLK - 1)) == 0) bptr[i / NBLK] = v;
    }
    if (i == 0) bptr[ntot / NBLK] = E;
}

// =================== contention-free bucket sort (bucket = dst >> SH, 256 nodes/bucket) ===================
// prologue: pre-swizzle W1/W2 into bf16 MFMA-fragment order in global ws (once, not per GEMM block)

__global__ __launch_bounds__(256) void k_histA(const int* __restrict__ dst, int* __restrict__ hmat,
                                               int E, int NB, int chunk,
                                               const float* __restrict__ W1, const float* __restrict__ W2,
                                               ushort_t* __restrict__ w1f, ushort_t* __restrict__ w2f) {
    __shared__ int h[MAXNB];
    int blk = blockIdx.x;
    // ---- W pre-swizzle (12288 elems over 65536 threads) ----
    int gid = blk * 256 + threadIdx.x;
    if (gid < 8192) {                                     // W1: [128][64]
        int k = gid >> 6, c = gid & 63;
        int f = ((k >> 5) << 2) | (c >> 4);
        int ln = (c & 15) | (((k >> 3) & 3) << 4);
        w1f[f * 512 + ln * 8 + (k & 7)] = f2bf(W1[gid]);
    } else if (gid < 12288) {                             // W2: [64][64]
        int i2 = gid - 8192;
        int k = i2 >> 6, c = i2 & 63;
        int f = ((k >> 5) << 2) | (c >> 4);
        int ln = (c & 15) | (((k >> 3) & 3) << 4);
        w2f[f * 512 + ln * 8 + (k & 7)] = f2bf(W2[i2]);
    }

    for (int i = threadIdx.x; i < NB; i += 256) h[i] = 0;
    __syncthreads();
    int beg = blk * chunk, end = beg + chunk; if (end > E) end = E;
    for (int e = beg + threadIdx.x; e < end; e += 256) atomicAdd(&h[dst[e] >> SH], 1);
    __syncthreads();
    for (int i = threadIdx.x; i < NB; i += 256) hmat[i * NBLK + blk] = h[i];
}

__global__ __launch_bounds__(256) void k_placeB(const int* __restrict__ src, const int* __restrict__ dst,
                                                const int* __restrict__ hmat, int* __restrict__ pairs,
                                                int E, int NB, int chunk) {
    __shared__ int cur[MAXNB];
    int blk = blockIdx.x;
    for (int i = threadIdx.x; i < NB; i += 256) cur[i] = hmat[i * NBLK + blk];
    __syncthreads();
    int beg = blk * chunk, end = beg + chunk; if (end > E) end = E;
    for (int e = beg + threadIdx.x; e < end; e += 256) {
        int s = src[e], d = dst[e];
        int off = atomicAdd(&cur[d >> SH], 1);
        pairs[off] = (s << SH) | (d & BMSK);
    }
}

// =================== fused CSR + GEMM1 (depth-2 pipelined) ===================
// One block per 256-node bucket:
//   phase 1: node hist + 256-scan -> row_ptr/cnt/dinv (dinv cached in LDS ds[])
//   phase 1.5: issue tile-0 X loads (8 float4) + all 16 A-frag loads (hidden under phase 2)
//   phase 2: col placement via LDS cursors
//   phase 3: hand-pipelined: load(tile q+1) || pack+MFMA+store(tile q)
__device__ __forceinline__ void load_tile(float4* u, const float* p) {
#pragma unroll
    for (int j = 0; j < 4; ++j) {
        u[2 * j]     = *(const float4*)(p + j * 32);
        u[2 * j + 1] = *(const float4*)(p + j * 32 + 4);
    }
}

__global__ __launch_bounds__(256) void k_csrmm(
    const int* __restrict__ bptr, const int* __restrict__ pairs,
    int* __restrict__ row_ptr, int* __restrict__ cnt,
    float* __restrict__ dinv, int* __restrict__ col,
    const float* __restrict__ X, const ushort_t* __restrict__ w1f,
    ushort_t* __restrict__ hsb, int n)
{
    __shared__ int h[256];
    __shared__ int cur[256];
    __shared__ float ds[256];
    __shared__ int ws[4];
    int b = blockIdx.x, t = threadIdx.x;
    h[t] = 0;
    __syncthreads();
    int beg = bptr[b], end = bptr[b + 1];
    for (int j = beg + t; j < end; j += 256) atomicAdd(&h[pairs[j] & BMSK], 1);
    __syncthreads();
    int c = h[t];
    int incl = wave_incl_scan(c, t & 63);
    if ((t & 63) == 63) ws[t >> 6] = incl;
    __syncthreads();
    int wofs = 0;
#pragma unroll
    for (int w = 0; w < 4; ++w) if (w < (t >> 6)) wofs += ws[w];
    int ex = wofs + incl - c;
    int node0 = b << SH;
    int node = node0 + t;
    float di_t = rsqrtf(1.0f + (float)c);
    if (node < n) {
        row_ptr[node] = beg + ex;
        cnt[node] = c;
        dinv[node] = di_t;
    }
    cur[t] = beg + ex;
    ds[t] = di_t;
    __syncthreads();

    // ---- phase 1.5: frag loads + tile-0 loads (in flight across phase 2) ----
    int lane = t & 63, wv = t >> 6;
    int r16 = lane & 15, kg = lane >> 4;
    const float* pX[4];
#pragma unroll
    for (int q = 0; q < 4; ++q) {
        int lrow = (wv + q * 4) * 16 + r16;
        int row = node0 + lrow;
        int r = (row < n) ? row : (n - 1);           // clamp: dup loads, stores guarded
        pX[q] = X + (size_t)r * 128 + kg * 8;
    }
    short8 a0[4], a1[4], a2[4], a3[4];
#pragma unroll
    for (int f = 0; f < 4; ++f) {
        a0[f] = *(const short8*)(w1f + (0 + f) * 512 + lane * 8);
        a1[f] = *(const short8*)(w1f + (4 + f) * 512 + lane * 8);
        a2[f] = *(const short8*)(w1f + (8 + f) * 512 + lane * 8);
        a3[f] = *(const short8*)(w1f + (12 + f) * 512 + lane * 8);
    }
    float4 uA[8], uB[8];
    load_tile(uA, pX[0]);

    // ---- phase 2: place col (loads above in flight) ----
    for (int j = beg + t; j < end; j += 256) {
        int pk = pairs[j];
        int p = atomicAdd(&cur[pk & BMSK], 1);
        col[p] = pk >> SH;
    }

    // ---- phase 3: depth-2 pipelined MFMA ----
#define MM_TILE(U, Q)                                                                   \
    {                                                                                   \
        short8 b0, b1, b2, b3;                                                          \
        PACK8(b0, U[0], U[1]); PACK8(b1, U[2], U[3]);                                   \
        PACK8(b2, U[4], U[5]); PACK8(b3, U[6], U[7]);                                   \
        f32x4 z = {0.f, 0.f, 0.f, 0.f};                                                 \
        f32x4 acc[4];                                                                   \
        _Pragma("unroll")                                                               \
        for (int f = 0; f < 4; ++f)                                                     \
            acc[f] = __builtin_amdgcn_mfma_f32_16x16x32_bf16(a0[f], b0, z, 0, 0, 0);    \
        _Pragma("unroll")                                                               \
        for (int f = 0; f < 4; ++f)                                                     \
            acc[f] = __builtin_amdgcn_mfma_f32_16x16x32_bf16(a1[f], b1, acc[f], 0, 0, 0);\
        _Pragma("unroll")                                                               \
        for (int f = 0; f < 4; ++f)                                                     \
            acc[f] = __builtin_amdgcn_mfma_f32_16x16x32_bf16(a2[f], b2, acc[f], 0, 0, 0);\
        _Pragma("unroll")                                                               \
        for (int f = 0; f < 4; ++f)                                                     \
            acc[f] = __builtin_amdgcn_mfma_f32_16x16x32_bf16(a3[f], b3, acc[f], 0, 0, 0);\
        int lrow = (wv + (Q) * 4) * 16 + r16;                                           \
        int row = node0 + lrow;                                                         \
        if (row < n) {                                                                  \
            float di = ds[lrow];                                                        \
            _Pragma("unroll")                                                           \
            for (int f = 0; f < 4; ++f) {                                               \
                ushort4 o;                                                              \
                o.x = f2bf(acc[f][0] * di); o.y = f2bf(acc[f][1] * di);                 \
                o.z = f2bf(acc[f][2] * di); o.w = f2bf(acc[f][3] * di);                 \
                *(ushort4*)(hsb + (size_t)row * NF + f * 16 + kg * 4) = o;              \
            }                                                                           \
        }                                                                               \
    }

    load_tile(uB, pX[1]);
    MM_TILE(uA, 0)
    load_tile(uA, pX[2]);
    MM_TILE(uB, 1)
    load_tile(uB, pX[3]);
    MM_TILE(uA, 2)
    MM_TILE(uB, 3)
#undef MM_TILE
}

// =================== fused pull1 + GEMM2 ===================
// Block = 256 threads = 16 dst nodes = one 16-row MFMA tile.
// Phase A (pull): act_row(d) = relu(dinv[d]*(hs[d]+sum hs[src])+b1), written in B-frag order
//   to LDS bfrag (2 KB). Phase B: A-frags from pre-swizzled global w2f (prefetched before
//   the gather loop); wave wv computes column slab [wv*16, wv*16+16).
__global__ __launch_bounds__(256) void k_pullmm(
    const ushort_t* __restrict__ hs, const float* __restrict__ dinv,
    const int* __restrict__ row_ptr, const int* __restrict__ cnt,
    const int* __restrict__ col, const float* __restrict__ bias,
    const ushort_t* __restrict__ w2f, ushort_t* __restrict__ out, int n)
{
    __shared__ ushort_t bfrag[1024];             // act tile in B-frag order (2 KB)
    int t = threadIdx.x;
    int lane = t & 63, wv = t >> 6;

    // prefetch A-frags (L2-resident; latency hides under the gather loop)
    short8 aflo = *(const short8*)(w2f + wv * 512 + lane * 8);
    short8 afhi = *(const short8*)(w2f + (4 + wv) * 512 + lane * 8);

    // ---- phase A: pull (one 16-lane group per node) ----
    int d = blockIdx.x * 16 + (t >> 4);
    int lt = t & 15;
    int fo = lt << 2;
    int grpbase = t & 48;
    const char* __restrict__ hp = (const char*)hs;
    unsigned lt8 = (unsigned)lt << 3;
    float rx = 0.f, ry = 0.f, rz = 0.f, rw = 0.f;
    if (d < n) {
        uint2 sv = *(const uint2*)(hp + (((unsigned)d << 7) + lt8));
        float4 acc = make_float4(bflo(sv.x), bfhi(sv.x), bflo(sv.y), bfhi(sv.y));
        int beg = row_ptr[d], deg = cnt[d];
        for (int jb = 0; jb < deg; jb += 16) {
            int m = deg - jb; if (m > 16) m = 16;
            int idx = (lt < m) ? col[beg + jb + lt] : 0;
            uint2 v[16];
#pragma unroll
            for (int u = 0; u < 16; ++u) {
                int kk = (u < m) ? u : (m - 1);              // clamp: dup loads hit L1
                int s = __shfl(idx, grpbase + kk, 64);
                v[u] = *(const uint2*)(hp + (((unsigned)s << 7) + lt8));
            }
#pragma unroll
            for (int u = 0; u < 16; ++u) {
                if (u < m) {
                    acc.x += bflo(v[u].x); acc.y += bfhi(v[u].x);
                    acc.z += bflo(v[u].y); acc.w += bfhi(v[u].y);
                }
            }
        }
        float di = dinv[d];
        float4 bv = *(const float4*)(bias + fo);
        rx = fmaxf(fmaf(acc.x, di, bv.x), 0.0f);
        ry = fmaxf(fmaf(acc.y, di, bv.y), 0.0f);
        rz = fmaxf(fmaf(acc.z, di, bv.z), 0.0f);
        rw = fmaxf(fmaf(acc.w, di, bv.w), 0.0f);
    }
    {
        ushort4 o;
        o.x = f2bf(rx); o.y = f2bf(ry); o.z = f2bf(rz); o.w = f2bf(rw);
        int g = t >> 4;
        int ks = lt >> 3, kg2 = (lt >> 1) & 3, half = lt & 1;
        *(ushort4*)(bfrag + ks * 512 + (((kg2 << 4) | g) << 3) + (half << 2)) = o;
    }
    __syncthreads();

    // ---- phase B: MFMA (wave wv -> columns [wv*16, wv*16+16)) ----
    int r16 = lane & 15, kg = lane >> 4;
    short8 bb0 = *(const short8*)(bfrag + lane * 8);         // ks=0, conflict-free
    short8 bb1 = *(const short8*)(bfrag + 512 + lane * 8);   // ks=1

    f32x4 z = {0.f, 0.f, 0.f, 0.f};
    f32x4 acc2 = __builtin_amdgcn_mfma_f32_16x16x32_bf16(aflo, bb0, z, 0, 0, 0);
    acc2 = __builtin_amdgcn_mfma_f32_16x16x32_bf16(afhi, bb1, acc2, 0, 0, 0);

    int row = blockIdx.x * 16 + r16;
    if (row < n) {
        float di = dinv[row];
        ushort4 o;
        o.x = f2bf(acc2[0] * di); o.y = f2bf(acc2[1] * di);
        o.z = f2bf(acc2[2] * di); o.w = f2bf(acc2[3] * di);
        *(ushort4*)((char*)out + (((unsigned)row << 7) + ((unsigned)wv << 5) + ((unsigned)kg << 3))) = o;
    }
}

// =================== pull2 + fused decode: out[d] = relu(dinv*(...)+b2) . Wd + bd ===================
__global__ __launch_bounds__(256) void k_pull2(
    const ushort_t* __restrict__ hs, const float* __restrict__ dinv,
    const int* __restrict__ row_ptr, const int* __restrict__ cnt,
    const int* __restrict__ col, const float* __restrict__ bias,
    const float* __restrict__ Wd, const float* __restrict__ bd,
    float* __restrict__ outv, int n)
{
    int d = blockIdx.x * 16 + (threadIdx.x >> 4);
    if (d >= n) return;
    int lt = threadIdx.x & 15;            // lane in group
    int fo = lt << 2;                     // feature offset (4 features/lane)
    int grpbase = threadIdx.x & 48;       // group base lane within wave
    const char* __restrict__ hp = (const char*)hs;
    unsigned lt8 = (unsigned)lt << 3;
    int beg = row_ptr[d], deg = cnt[d];

    // self-loop (bf16 row, 8B/lane)
    uint2 sv = *(const uint2*)(hp + (((unsigned)d << 7) + lt8));
    float4 acc = make_float4(bflo(sv.x), bfhi(sv.x), bflo(sv.y), bfhi(sv.y));

    for (int jb = 0; jb < deg; jb += 16) {
        int m = deg - jb; if (m > 16) m = 16;
        int idx = (lt < m) ? col[beg + jb + lt] : 0;
        uint2 v[16];
#pragma unroll
        for (int u = 0; u < 16; ++u) {
            int kk = (u < m) ? u : (m - 1);                  // clamp: dup loads hit L1
            int s = __shfl(idx, grpbase + kk, 64);
            v[u] = *(const uint2*)(hp + (((unsigned)s << 7) + lt8));
        }
#pragma unroll
        for (int u = 0; u < 16; ++u) {
            if (u < m) {
                acc.x += bflo(v[u].x); acc.y += bfhi(v[u].x);
                acc.z += bflo(v[u].y); acc.w += bfhi(v[u].y);
            }
        }
    }

    float di = dinv[d];
    float4 bv = *(const float4*)(bias + fo);
    float rx = fmaxf(fmaf(acc.x, di, bv.x), 0.0f);
    float ry = fmaxf(fmaf(acc.y, di, bv.y), 0.0f);
    float rz = fmaxf(fmaf(acc.z, di, bv.z), 0.0f);
    float rw = fmaxf(fmaf(acc.w, di, bv.w), 0.0f);

    float4 wv = *(const float4*)(Wd + fo);
    float vsum = rx * wv.x + ry * wv.y + rz * wv.z + rw * wv.w;
#pragma unroll
    for (int o = 1; o < 16; o <<= 1) vsum += __shfl_xor(vsum, o, 64);
    if (lt == 0) outv[d] = vsum + bd[0];
}

extern "C" void kernel_launch(void* const* d_in, const int* in_sizes, int n_in,
                              void* d_out, int out_size, void* d_ws, size_t ws_size,
                              hipStream_t stream) {
    const float* x  = (const float*)d_in[0];
    const int*   ei = (const int*)d_in[1];
    const float* W1 = (const float*)d_in[2];
    const float* b1 = (const float*)d_in[3];
    const float* W2 = (const float*)d_in[4];
    const float* b2 = (const float*)d_in[5];
    const float* Wd = (const float*)d_in[6];
    const float* bd = (const float*)d_in[7];
    float* out = (float*)d_out;

    int n = in_sizes[0] / 128;
    int E = in_sizes[1] / 2;
    const int* src = ei;
    const int* dst = ei + E;

    int NB = (n + (1 << SH) - 1) >> SH;     // dst buckets of 256 nodes (~391)
    int chunk = (E + NBLK - 1) / NBLK;
    int ntot = NB * NBLK;                   // hist matrix size (~100k)
    int nsb = (ntot + 1023) / 1024;         // scan blocks over hmat (<= 2048)

    // workspace layout (4-byte elems)
    // bufH: hsb. bufA: hs2b (lower half) + pairs (upper half).
    // pairs is read by k_csrmm while it writes hsb -> must not alias bufH.
    float* dinv    = (float*)d_ws;                    // n
    float* bufH    = dinv + n;                        // 64n f32 region
    float* bufA    = bufH + (size_t)n * NF;           // 64n f32 region
    int*   counts  = (int*)(bufA + (size_t)n * NF);   // n
    int*   row_ptr = counts + n;                      // n
    int*   col     = row_ptr + n;                     // E
    int*   hmat    = col + E;                         // NB*NBLK
    int*   bptr    = hmat + ntot;                     // NB+1
    int*   bsums   = bptr + NB + 1;                   // <=2048
    int*   wfrags  = bsums + 2048;                    // 6144 ints: w1f (4096) + w2f (2048)
    ushort_t* w1f  = (ushort_t*)wfrags;               // 8192 bf16 pre-swizzled W1 frags
    ushort_t* w2f  = w1f + 8192;                      // 4096 bf16 pre-swizzled W2 frags
    ushort_t* hsb  = (ushort_t*)bufH;                 // 64n bf16 layer-1 hs
    ushort_t* hs2b = (ushort_t*)bufA;                 // 64n bf16 layer-2 hs (lower 32n f32)
    int*   pairs   = (int*)(bufA + (size_t)n * 32);   // E ints in upper half of bufA region

    // ---- bucket sort by dst (contention-free) + W frag pre-swizzle ----
    k_histA<<<NBLK, 256, 0, stream>>>(dst, hmat, E, NB, chunk, W1, W2, w1f, w2f);
    k_scan_a<<<nsb, 256, 0, stream>>>(hmat, hmat, bsums, ntot);
    k_scan_addb<<<(ntot + 255) / 256, 256, 0, stream>>>(hmat, bsums, bptr, ntot, E);
    k_placeB<<<NBLK, 256, 0, stream>>>(src, dst, hmat, pairs, E, NB, chunk);

    // ---- fused node CSR + dinv + GEMM1 (MFMA, depth-2 pipelined) ----
    k_csrmm<<<NB, 256, 0, stream>>>(bptr, pairs, row_ptr, counts, dinv, col,
                                    x, w1f, hsb, n);

    // ---- fused pull1 (+b1, relu) + GEMM2 (MFMA): hs2 = bf16((act @ W2) * dinv) ----
    k_pullmm<<<(n + 15) / 16, 256, 0, stream>>>(hsb, dinv, row_ptr, counts, col, b1,
                                                w2f, hs2b, n);

    // ---- pull2 (+b2, relu) + fused decode ----
    k_pull2<<<(n + 15) / 16, 256, 0, stream>>>(hs2b, dinv, row_ptr, counts, col, b2,
                                               Wd, bd, out, n);
}